// Round 8
// baseline (197.835 us; speedup 1.0000x reference)
//
#include <hip/hip_runtime.h>

#define NN 4096
#define IN_DIM 256
#define HID 64
#define HEADS 8

typedef __attribute__((ext_vector_type(4))) float f32x4;
typedef __attribute__((ext_vector_type(8))) short s16x8;
typedef unsigned short u16;
typedef unsigned long long u64;

__device__ inline u16 f2bf(float f) {
  union { float f; unsigned u; } v; v.f = f;
  unsigned r = (v.u + 0x7FFFu + ((v.u >> 16) & 1u)) >> 16;
  return (u16)r;
}
__device__ inline float bf2f(u16 b) {
  union { unsigned u; float f; } v; v.u = ((unsigned)b) << 16;
  return v.f;
}
__device__ __forceinline__ unsigned cvt_pk_bf16(float a, float b) {
  unsigned r;
  asm("v_cvt_pk_bf16_f32 %0, %1, %2" : "=v"(r) : "v"(a), "v"(b));
  return r;  // lo = bf16(a), hi = bf16(b)
}

// ---------------------------------------------------------------------------
// Kernel 0: detect adjacency element width (uint8 / int32 / int64).
// ---------------------------------------------------------------------------
__global__ void gat_detect(const void* __restrict__ adj, int* __restrict__ flag)
{
  const int lane = threadIdx.x;
  const unsigned char* a8 = (const unsigned char*)adj;
  const int* a32 = (const int*)adj;

  size_t i8 = (size_t)(4 * lane + 1) * 4097;      // diag byte if u8
  int p8 = a8[i8] != 0;

  size_t k = (size_t)(2 * lane + 1);              // odd
  int p32 = a32[k * 4097] != 0;                   // diag elem if i32
  int p64 = a32[2 * k * 4097] != 0;               // low word of diag if i64

  int ok8 = __all(p8), ok32 = __all(p32), ok64 = __all(p64);
  if (lane == 0) *flag = ok8 ? 0 : (ok32 ? 1 : (ok64 ? 2 : 1));
}

// ---------------------------------------------------------------------------
// Kernel 0b: pack adjacency into bitmask [4096 rows][64 u64 words].
// ---------------------------------------------------------------------------
__global__ __launch_bounds__(256) void gat_pack(
    const void* __restrict__ adj, const int* __restrict__ flag,
    u64* __restrict__ bits)
{
  const int mode = *flag;
  const int lane = threadIdx.x & 63;
  const int wave = (blockIdx.x * blockDim.x + threadIdx.x) >> 6;
  const int nwaves = (gridDim.x * blockDim.x) >> 6;
  const size_t nwords = (size_t)NN * NN / 64;

  for (size_t w = wave; w < nwords; w += nwaves) {
    size_t e = w * 64 + lane;
    int on;
    if (mode == 1)      on = ((const int*)adj)[e] != 0;
    else if (mode == 0) on = ((const unsigned char*)adj)[e] != 0;
    else                on = ((const long long*)adj)[e] != 0;
    u64 b = __ballot(on);
    if (lane == 0) bits[w] = b;
  }
}

// ---------------------------------------------------------------------------
// Kernel 1: H = x @ W^T  (4096 x 512), f32 out + TILED bf16 copy:
// Hbt2[h][jt][f][j_in] -- one contiguous 8KB block per (head, 64-col j-tile).
// ---------------------------------------------------------------------------
__global__ __launch_bounds__(256) void gat_gemm1(
    const float* __restrict__ x, const float* __restrict__ W,
    float* __restrict__ Hf, u16* __restrict__ Hbt)
{
  __shared__ u16 xhi[64 * 72], xlo[64 * 72], whi[64 * 72], wlo[64 * 72];
  const int nb = blockIdx.x;   // node block (rows) == j-tile index
  const int ob = blockIdx.y;   // out block  (cols) == head
  const int t = threadIdx.x;
  const int lane = t & 63, wid = t >> 6;
  const int wr = wid >> 1, wc = wid & 1;
  const int g = lane >> 4;

  f32x4 acc[2][2] = {};

  const int sn = t >> 2;          // staging row 0..63
  const int skc = (t & 3) * 16;   // staging k offset within 64-chunk

  for (int kb = 0; kb < 4; ++kb) {
    const float* xr = x + (size_t)(nb * 64 + sn) * IN_DIM + kb * 64 + skc;
    const float* wr_p = W + (size_t)(ob * 64 + sn) * IN_DIM + kb * 64 + skc;
#pragma unroll
    for (int c = 0; c < 4; ++c) {
      float4 xv = ((const float4*)xr)[c];
      float4 wv = ((const float4*)wr_p)[c];
      float xf[4] = {xv.x, xv.y, xv.z, xv.w};
      float wf[4] = {wv.x, wv.y, wv.z, wv.w};
      u16 xh[4], xl[4], wh[4], wl[4];
#pragma unroll
      for (int e = 0; e < 4; ++e) {
        xh[e] = f2bf(xf[e]); xl[e] = f2bf(xf[e] - bf2f(xh[e]));
        wh[e] = f2bf(wf[e]); wl[e] = f2bf(wf[e] - bf2f(wh[e]));
      }
      int base = sn * 72 + skc + c * 4;
      *(ushort4*)(xhi + base) = make_ushort4(xh[0], xh[1], xh[2], xh[3]);
      *(ushort4*)(xlo + base) = make_ushort4(xl[0], xl[1], xl[2], xl[3]);
      *(ushort4*)(whi + base) = make_ushort4(wh[0], wh[1], wh[2], wh[3]);
      *(ushort4*)(wlo + base) = make_ushort4(wl[0], wl[1], wl[2], wl[3]);
    }
    __syncthreads();
#pragma unroll
    for (int ks = 0; ks < 2; ++ks) {
      const int k0 = ks * 32 + g * 8;
      s16x8 ah[2], al[2], bh[2], bl[2];
#pragma unroll
      for (int nf = 0; nf < 2; ++nf) {
        int row = wr * 32 + nf * 16 + (lane & 15);
        ah[nf] = *(const s16x8*)(xhi + row * 72 + k0);
        al[nf] = *(const s16x8*)(xlo + row * 72 + k0);
      }
#pragma unroll
      for (int of = 0; of < 2; ++of) {
        int row = wc * 32 + of * 16 + (lane & 15);
        bh[of] = *(const s16x8*)(whi + row * 72 + k0);
        bl[of] = *(const s16x8*)(wlo + row * 72 + k0);
      }
#pragma unroll
      for (int nf = 0; nf < 2; ++nf)
#pragma unroll
        for (int of = 0; of < 2; ++of) {
          acc[nf][of] = __builtin_amdgcn_mfma_f32_16x16x32_bf16(ah[nf], bh[of], acc[nf][of], 0, 0, 0);
          acc[nf][of] = __builtin_amdgcn_mfma_f32_16x16x32_bf16(ah[nf], bl[of], acc[nf][of], 0, 0, 0);
          acc[nf][of] = __builtin_amdgcn_mfma_f32_16x16x32_bf16(al[nf], bh[of], acc[nf][of], 0, 0, 0);
        }
    }
    __syncthreads();
  }

  // epilogue: f32 H + tiled bf16 copy (via LDS, reuse xhi)
#pragma unroll
  for (int nf = 0; nf < 2; ++nf)
#pragma unroll
    for (int of = 0; of < 2; ++of)
#pragma unroll
      for (int r = 0; r < 4; ++r) {
        int nloc = wr * 32 + nf * 16 + g * 4 + r;
        int oloc = wc * 32 + of * 16 + (lane & 15);
        Hf[(size_t)(nb * 64 + nloc) * 512 + ob * 64 + oloc] = acc[nf][of][r];
      }
  u16* Ct = xhi;  // [64 o][72 n]
#pragma unroll
  for (int nf = 0; nf < 2; ++nf)
#pragma unroll
    for (int of = 0; of < 2; ++of)
#pragma unroll
      for (int r = 0; r < 4; ++r) {
        int nloc = wr * 32 + nf * 16 + g * 4 + r;
        int oloc = wc * 32 + of * 16 + (lane & 15);
        Ct[oloc * 72 + nloc] = f2bf(acc[nf][of][r]);
      }
  __syncthreads();
  {
    int o = t >> 2, nc = (t & 3) * 16;
    u16* dst = Hbt + ((size_t)(ob * 64 + nb) * 64 + o) * 64 + nc;
#pragma unroll
    for (int c = 0; c < 2; ++c) {
      s16x8 v = *(const s16x8*)(Ct + o * 72 + nc + c * 8);
      *(s16x8*)(dst + c * 8) = v;
    }
  }
}

// ---------------------------------------------------------------------------
// Kernel 2: src/dst attention scores -> transposed layout [h][node].
// ---------------------------------------------------------------------------
__global__ __launch_bounds__(256) void gat_scores(
    const float* __restrict__ Hf, const float* __restrict__ a_src,
    const float* __restrict__ a_dst, float* __restrict__ s_srcT,
    float* __restrict__ s_dstT)
{
  int node = blockIdx.x * 4 + (threadIdx.x >> 6);
  int lane = threadIdx.x & 63;
  int h = lane >> 3, c = lane & 7;
  const float* hrow = Hf + (size_t)node * 512 + h * 64 + c * 8;
  const float* as = a_src + h * 64 + c * 8;
  const float* ad = a_dst + h * 64 + c * 8;
  float vs = 0.f, vd = 0.f;
#pragma unroll
  for (int e = 0; e < 8; ++e) { float hv = hrow[e]; vs += hv * as[e]; vd += hv * ad[e]; }
#pragma unroll
  for (int m = 1; m < 8; m <<= 1) { vs += __shfl_xor(vs, m); vd += __shfl_xor(vd, m); }
  if (c == 0) { s_srcT[h * NN + node] = vs; s_dstT[h * NN + node] = vd; }
}

// ---------------------------------------------------------------------------
// Kernel 2b: per-head global max of dst scores (upper bound for fixed-m).
// ---------------------------------------------------------------------------
__global__ __launch_bounds__(512) void gat_dmax(
    const float* __restrict__ s_dstT, float* __restrict__ Mh)
{
  const int w = threadIdx.x >> 6, lane = threadIdx.x & 63;
  const float* p = s_dstT + (size_t)w * NN;
  float m = -INFINITY;
#pragma unroll
  for (int it = 0; it < 16; ++it) {
    f32x4 v = *(const f32x4*)(p + (it * 64 + lane) * 4);
    m = fmaxf(fmaxf(fmaxf(m, v[0]), v[1]), fmaxf(v[2], v[3]));
  }
#pragma unroll
  for (int s = 1; s < 64; s <<= 1) m = fmaxf(m, __shfl_xor(m, s));
  if (lane == 0) Mh[w] = m;
}

// ---------------------------------------------------------------------------
// Kernel 3: flash-GAT, fixed-m softmax, head-split grid for full occupancy:
// grid (256 i-blocks, 2 head-groups), 512 threads = 8 waves = 4 heads x 2
// j-halves -> 4 blocks/CU = 32 waves/CU. Each block writes a 4-head
// normalized partial to pout[hg]; combine kernel adds the two groups.
// ---------------------------------------------------------------------------
__global__ __launch_bounds__(512, 8) void gat_flash(
    const u64* __restrict__ bits, const u16* __restrict__ Hbt,
    const float* __restrict__ s_srcT, const float* __restrict__ s_dstT,
    const float* __restrict__ Mh, float* __restrict__ pout)
{
  __shared__ float Abuf[4][16][66];   // padded: conflict-free
  __shared__ float Lbuf[4][16];

  const int t = threadIdx.x, lane = t & 63, w = t >> 6;
  const int h4 = w & 3, jsw = w >> 2;
  const int blk = blockIdx.x, hg = blockIdx.y;
  const int h = hg * 4 + h4;
  const int i_loc = lane & 15, g = lane >> 4, j0 = g * 8;

  const float s_i = s_srcT[(size_t)h * NN + blk * 16 + i_loc];
  float m_i = s_i + Mh[h];
  m_i = fmaxf(m_i, 0.2f * m_i);                 // lrelu(s_i + M_h) >= all z
  const float L2E = 1.44269504f;
  const float mL = m_i * L2E;

  // tiled A: lane base within a (h,jt) 4096-elem tile
  const u16* hb0 = Hbt + (size_t)h * 64 * 4096 + i_loc * 64 + j0;
  const float* dT = s_dstT + (size_t)h * NN;
  const u64* brow = bits + (size_t)(blk * 16 + i_loc) * 64;

  f32x4 acc[4] = {};
  f32x4 lacc = {0.f, 0.f, 0.f, 0.f};

  const int jt0 = jsw * 32, jt1 = jt0 + 32;

#define LOADA(BUF, JT) do {                                           \
    const u16* p_ = hb0 + (size_t)(JT) * 4096;                        \
    _Pragma("unroll")                                                 \
    for (int fb = 0; fb < 4; ++fb) {                                  \
      BUF[fb][0] = *(const s16x8*)(p_ + fb * 1024);                   \
      BUF[fb][1] = *(const s16x8*)(p_ + fb * 1024 + 32);              \
    }                                                                 \
  } while (0)

#define QUAD(DP, MBITS, SH, PW0, PW1, LI) do {                        \
    f32x4 dv_ = *(const f32x4*)(DP);                                  \
    float z0 = s_i + dv_[0], z1 = s_i + dv_[1];                       \
    float z2 = s_i + dv_[2], z3 = s_i + dv_[3];                       \
    z0 = fmaxf(z0, 0.2f * z0); z1 = fmaxf(z1, 0.2f * z1);             \
    z2 = fmaxf(z2, 0.2f * z2); z3 = fmaxf(z3, 0.2f * z3);             \
    float e0 = __builtin_amdgcn_exp2f(__builtin_fmaf(z0, L2E, -mL));  \
    float e1 = __builtin_amdgcn_exp2f(__builtin_fmaf(z1, L2E, -mL));  \
    float e2 = __builtin_amdgcn_exp2f(__builtin_fmaf(z2, L2E, -mL));  \
    float e3 = __builtin_amdgcn_exp2f(__builtin_fmaf(z3, L2E, -mL));  \
    e0 = ((MBITS >> (SH + 0)) & 1u) ? e0 : 0.f;                       \
    e1 = ((MBITS >> (SH + 1)) & 1u) ? e1 : 0.f;                       \
    e2 = ((MBITS >> (SH + 2)) & 1u) ? e2 : 0.f;                       \
    e3 = ((MBITS >> (SH + 3)) & 1u) ? e3 : 0.f;                       \
    lacc[LI] += (e0 + e1) + (e2 + e3);                                \
    PW0 = cvt_pk_bf16(e0, e1); PW1 = cvt_pk_bf16(e2, e3);             \
  } while (0)

#define TILE(BUF, JT, JNEXT) do {                                     \
    const u64 am_ = am_n;                                             \
    am_n = brow[JNEXT];                                               \
    const float* dp_ = dT + (JT) * 64 + j0;                           \
    const unsigned amlo_ = (unsigned)(am_ >> j0);                     \
    const unsigned amhi_ = (unsigned)(am_ >> (32 + j0));              \
    union { unsigned w_[4]; s16x8 v_; } P0, P1;                       \
    QUAD(dp_,      amlo_, 0, P0.w_[0], P0.w_[1], 0);                  \
    QUAD(dp_ + 4,  amlo_, 4, P0.w_[2], P0.w_[3], 1);                  \
    QUAD(dp_ + 32, amhi_, 0, P1.w_[0], P1.w_[1], 2);                  \
    QUAD(dp_ + 36, amhi_, 4, P1.w_[2], P1.w_[3], 3);                  \
    _Pragma("unroll")                                                 \
    for (int fb = 0; fb < 4; ++fb) {                                  \
      acc[fb] = __builtin_amdgcn_mfma_f32_16x16x32_bf16(BUF[fb][0], P0.v_, acc[fb], 0, 0, 0); \
      acc[fb] = __builtin_amdgcn_mfma_f32_16x16x32_bf16(BUF[fb][1], P1.v_, acc[fb], 0, 0, 0); \
    }                                                                 \
  } while (0)

  s16x8 buf[4][2];
  u64 am_n = brow[jt0];

  for (int jt = jt0; jt < jt1; ++jt) {
    LOADA(buf, jt);
    const int jn = (jt + 1 < jt1) ? jt + 1 : jt;
    TILE(buf, jt, jn);
  }
#undef LOADA
#undef QUAD
#undef TILE

  // l for this wave's j-half: sum 4 partials, then over the 4 g-groups
  float l_run = (lacc[0] + lacc[1]) + (lacc[2] + lacc[3]);
  l_run += __shfl_xor(l_run, 16);
  l_run += __shfl_xor(l_run, 32);

  // epilogue: plain-add merge of the two j-halves (same m!), then 4-head sum
  if (jsw == 1) {
#pragma unroll
    for (int fb = 0; fb < 4; ++fb)
#pragma unroll
      for (int r = 0; r < 4; ++r)
        Abuf[h4][i_loc][fb * 16 + g * 4 + r] = acc[fb][r];
    if (lane < 16) Lbuf[h4][i_loc] = l_run;
  }
  __syncthreads();
  if (jsw == 0) {
    float invL = 1.f / (l_run + Lbuf[h4][i_loc]);
#pragma unroll
    for (int fb = 0; fb < 4; ++fb)
#pragma unroll
      for (int r = 0; r < 4; ++r) {
        int f = fb * 16 + g * 4 + r;
        Abuf[h4][i_loc][f] = (acc[fb][r] + Abuf[h4][i_loc][f]) * invL;
      }
  }
  __syncthreads();
#pragma unroll
  for (int e = t; e < 1024; e += 512) {
    int i = e >> 6, f = e & 63;
    float s = (Abuf[0][i][f] + Abuf[1][i][f]) + (Abuf[2][i][f] + Abuf[3][i][f]);
    pout[((size_t)hg * NN + blk * 16 + i) * 64 + f] = s;
  }
}

// ---------------------------------------------------------------------------
// Kernel 4: combine the two head-group partials, apply 1/8 head-mean.
// ---------------------------------------------------------------------------
__global__ __launch_bounds__(256) void gat_combine(
    const float* __restrict__ pout, float* __restrict__ out)
{
  size_t e = (size_t)blockIdx.x * 256 + threadIdx.x;   // f32x4 index
  f32x4 a = ((const f32x4*)pout)[e];
  f32x4 b = ((const f32x4*)(pout + (size_t)NN * 64))[e];
  f32x4 r = (a + b) * 0.125f;
  ((f32x4*)out)[e] = r;
}

extern "C" void kernel_launch(void* const* d_in, const int* in_sizes, int n_in,
                              void* d_out, int out_size, void* d_ws, size_t ws_size,
                              hipStream_t stream)
{
  const float* x = (const float*)d_in[0];
  const void* adj = d_in[1];
  const float* W = (const float*)d_in[2];
  const float* a_src = (const float*)d_in[3];
  const float* a_dst = (const float*)d_in[4];
  float* out = (float*)d_out;

  char* ws = (char*)d_ws;
  float* Hf = (float*)ws;                                   // 8 MB (pout aliases this after scores)
  u16* Hbt = (u16*)(ws + 8 * 1024 * 1024);                  // 4 MB  [8][64][64][64] bf16 tiled
  float* s_srcT = (float*)(ws + 12 * 1024 * 1024);          // 128 KB [8][4096]
  float* s_dstT = (float*)(ws + 12 * 1024 * 1024 + 128 * 1024);
  int* flag = (int*)(ws + 12 * 1024 * 1024 + 256 * 1024);
  float* Mh = (float*)(ws + 12 * 1024 * 1024 + 384 * 1024); // 32 B
  u64* bits = (u64*)(ws + 12 * 1024 * 1024 + 512 * 1024);   // 2 MB
  float* pout = (float*)ws;                                 // alias Hf (dead after gat_scores)

  gat_detect<<<1, 64, 0, stream>>>(adj, flag);
  gat_pack<<<2048, 256, 0, stream>>>(adj, flag, bits);
  gat_gemm1<<<dim3(64, 8), 256, 0, stream>>>(x, W, Hf, Hbt);
  gat_scores<<<1024, 256, 0, stream>>>(Hf, a_src, a_dst, s_srcT, s_dstT);
  gat_dmax<<<1, 512, 0, stream>>>(s_dstT, Mh);
  gat_flash<<<dim3(256, 2), 512, 0, stream>>>(bits, Hbt, s_srcT, s_dstT, Mh, pout);
  gat_combine<<<256, 256, 0, stream>>>(pout, out);
}

// Round 9
// 110.393 us; speedup vs baseline: 1.7921x; 1.7921x over previous
//
#include <hip/hip_runtime.h>

#define NN 4096
#define IN_DIM 256
#define HID 64
#define HEADS 8

typedef __attribute__((ext_vector_type(4))) float f32x4;
typedef __attribute__((ext_vector_type(8))) short s16x8;
typedef unsigned short u16;
typedef unsigned long long u64;

__device__ inline u16 f2bf(float f) {
  union { float f; unsigned u; } v; v.f = f;
  unsigned r = (v.u + 0x7FFFu + ((v.u >> 16) & 1u)) >> 16;
  return (u16)r;
}
__device__ inline float bf2f(u16 b) {
  union { unsigned u; float f; } v; v.u = ((unsigned)b) << 16;
  return v.f;
}
__device__ __forceinline__ unsigned cvt_pk_bf16(float a, float b) {
  unsigned r;
  asm("v_cvt_pk_bf16_f32 %0, %1, %2" : "=v"(r) : "v"(a), "v"(b));
  return r;  // lo = bf16(a), hi = bf16(b)
}

// ---------------------------------------------------------------------------
// Kernel 0: detect adjacency element width (uint8 / int32 / int64).
// ---------------------------------------------------------------------------
__global__ void gat_detect(const void* __restrict__ adj, int* __restrict__ flag)
{
  const int lane = threadIdx.x;
  const unsigned char* a8 = (const unsigned char*)adj;
  const int* a32 = (const int*)adj;

  size_t i8 = (size_t)(4 * lane + 1) * 4097;      // diag byte if u8
  int p8 = a8[i8] != 0;

  size_t k = (size_t)(2 * lane + 1);              // odd
  int p32 = a32[k * 4097] != 0;                   // diag elem if i32
  int p64 = a32[2 * k * 4097] != 0;               // low word of diag if i64

  int ok8 = __all(p8), ok32 = __all(p32), ok64 = __all(p64);
  if (lane == 0) *flag = ok8 ? 0 : (ok32 ? 1 : (ok64 ? 2 : 1));
}

// ---------------------------------------------------------------------------
// Kernel 0b: pack adjacency into bitmask [4096 rows][64 u64 words].
// ---------------------------------------------------------------------------
__global__ __launch_bounds__(256) void gat_pack(
    const void* __restrict__ adj, const int* __restrict__ flag,
    u64* __restrict__ bits)
{
  const int mode = *flag;
  const int lane = threadIdx.x & 63;
  const int wave = (blockIdx.x * blockDim.x + threadIdx.x) >> 6;
  const int nwaves = (gridDim.x * blockDim.x) >> 6;
  const size_t nwords = (size_t)NN * NN / 64;

  for (size_t w = wave; w < nwords; w += nwaves) {
    size_t e = w * 64 + lane;
    int on;
    if (mode == 1)      on = ((const int*)adj)[e] != 0;
    else if (mode == 0) on = ((const unsigned char*)adj)[e] != 0;
    else                on = ((const long long*)adj)[e] != 0;
    u64 b = __ballot(on);
    if (lane == 0) bits[w] = b;
  }
}

// ---------------------------------------------------------------------------
// Kernel 1: H = x @ W^T  (4096 x 512), f32 out + TILED bf16 copy:
// Hbt2[h][jt][f][j_in] -- one contiguous 8KB block per (head, 64-col j-tile).
// ---------------------------------------------------------------------------
__global__ __launch_bounds__(256) void gat_gemm1(
    const float* __restrict__ x, const float* __restrict__ W,
    float* __restrict__ Hf, u16* __restrict__ Hbt)
{
  __shared__ u16 xhi[64 * 72], xlo[64 * 72], whi[64 * 72], wlo[64 * 72];
  const int nb = blockIdx.x;   // node block (rows) == j-tile index
  const int ob = blockIdx.y;   // out block  (cols) == head
  const int t = threadIdx.x;
  const int lane = t & 63, wid = t >> 6;
  const int wr = wid >> 1, wc = wid & 1;
  const int g = lane >> 4;

  f32x4 acc[2][2] = {};

  const int sn = t >> 2;          // staging row 0..63
  const int skc = (t & 3) * 16;   // staging k offset within 64-chunk

  for (int kb = 0; kb < 4; ++kb) {
    const float* xr = x + (size_t)(nb * 64 + sn) * IN_DIM + kb * 64 + skc;
    const float* wr_p = W + (size_t)(ob * 64 + sn) * IN_DIM + kb * 64 + skc;
#pragma unroll
    for (int c = 0; c < 4; ++c) {
      float4 xv = ((const float4*)xr)[c];
      float4 wv = ((const float4*)wr_p)[c];
      float xf[4] = {xv.x, xv.y, xv.z, xv.w};
      float wf[4] = {wv.x, wv.y, wv.z, wv.w};
      u16 xh[4], xl[4], wh[4], wl[4];
#pragma unroll
      for (int e = 0; e < 4; ++e) {
        xh[e] = f2bf(xf[e]); xl[e] = f2bf(xf[e] - bf2f(xh[e]));
        wh[e] = f2bf(wf[e]); wl[e] = f2bf(wf[e] - bf2f(wh[e]));
      }
      int base = sn * 72 + skc + c * 4;
      *(ushort4*)(xhi + base) = make_ushort4(xh[0], xh[1], xh[2], xh[3]);
      *(ushort4*)(xlo + base) = make_ushort4(xl[0], xl[1], xl[2], xl[3]);
      *(ushort4*)(whi + base) = make_ushort4(wh[0], wh[1], wh[2], wh[3]);
      *(ushort4*)(wlo + base) = make_ushort4(wl[0], wl[1], wl[2], wl[3]);
    }
    __syncthreads();
#pragma unroll
    for (int ks = 0; ks < 2; ++ks) {
      const int k0 = ks * 32 + g * 8;
      s16x8 ah[2], al[2], bh[2], bl[2];
#pragma unroll
      for (int nf = 0; nf < 2; ++nf) {
        int row = wr * 32 + nf * 16 + (lane & 15);
        ah[nf] = *(const s16x8*)(xhi + row * 72 + k0);
        al[nf] = *(const s16x8*)(xlo + row * 72 + k0);
      }
#pragma unroll
      for (int of = 0; of < 2; ++of) {
        int row = wc * 32 + of * 16 + (lane & 15);
        bh[of] = *(const s16x8*)(whi + row * 72 + k0);
        bl[of] = *(const s16x8*)(wlo + row * 72 + k0);
      }
#pragma unroll
      for (int nf = 0; nf < 2; ++nf)
#pragma unroll
        for (int of = 0; of < 2; ++of) {
          acc[nf][of] = __builtin_amdgcn_mfma_f32_16x16x32_bf16(ah[nf], bh[of], acc[nf][of], 0, 0, 0);
          acc[nf][of] = __builtin_amdgcn_mfma_f32_16x16x32_bf16(ah[nf], bl[of], acc[nf][of], 0, 0, 0);
          acc[nf][of] = __builtin_amdgcn_mfma_f32_16x16x32_bf16(al[nf], bh[of], acc[nf][of], 0, 0, 0);
        }
    }
    __syncthreads();
  }

  // epilogue: f32 H + tiled bf16 copy (via LDS, reuse xhi)
#pragma unroll
  for (int nf = 0; nf < 2; ++nf)
#pragma unroll
    for (int of = 0; of < 2; ++of)
#pragma unroll
      for (int r = 0; r < 4; ++r) {
        int nloc = wr * 32 + nf * 16 + g * 4 + r;
        int oloc = wc * 32 + of * 16 + (lane & 15);
        Hf[(size_t)(nb * 64 + nloc) * 512 + ob * 64 + oloc] = acc[nf][of][r];
      }
  u16* Ct = xhi;  // [64 o][72 n]
#pragma unroll
  for (int nf = 0; nf < 2; ++nf)
#pragma unroll
    for (int of = 0; of < 2; ++of)
#pragma unroll
      for (int r = 0; r < 4; ++r) {
        int nloc = wr * 32 + nf * 16 + g * 4 + r;
        int oloc = wc * 32 + of * 16 + (lane & 15);
        Ct[oloc * 72 + nloc] = f2bf(acc[nf][of][r]);
      }
  __syncthreads();
  {
    int o = t >> 2, nc = (t & 3) * 16;
    u16* dst = Hbt + ((size_t)(ob * 64 + nb) * 64 + o) * 64 + nc;
#pragma unroll
    for (int c = 0; c < 2; ++c) {
      s16x8 v = *(const s16x8*)(Ct + o * 72 + nc + c * 8);
      *(s16x8*)(dst + c * 8) = v;
    }
  }
}

// ---------------------------------------------------------------------------
// Kernel 2: src/dst attention scores -> transposed layout [h][node].
// ---------------------------------------------------------------------------
__global__ __launch_bounds__(256) void gat_scores(
    const float* __restrict__ Hf, const float* __restrict__ a_src,
    const float* __restrict__ a_dst, float* __restrict__ s_srcT,
    float* __restrict__ s_dstT)
{
  int node = blockIdx.x * 4 + (threadIdx.x >> 6);
  int lane = threadIdx.x & 63;
  int h = lane >> 3, c = lane & 7;
  const float* hrow = Hf + (size_t)node * 512 + h * 64 + c * 8;
  const float* as = a_src + h * 64 + c * 8;
  const float* ad = a_dst + h * 64 + c * 8;
  float vs = 0.f, vd = 0.f;
#pragma unroll
  for (int e = 0; e < 8; ++e) { float hv = hrow[e]; vs += hv * as[e]; vd += hv * ad[e]; }
#pragma unroll
  for (int m = 1; m < 8; m <<= 1) { vs += __shfl_xor(vs, m); vd += __shfl_xor(vd, m); }
  if (c == 0) { s_srcT[h * NN + node] = vs; s_dstT[h * NN + node] = vd; }
}

// ---------------------------------------------------------------------------
// Kernel 2b: per-head global max of dst scores (upper bound for fixed-m).
// ---------------------------------------------------------------------------
__global__ __launch_bounds__(512) void gat_dmax(
    const float* __restrict__ s_dstT, float* __restrict__ Mh)
{
  const int w = threadIdx.x >> 6, lane = threadIdx.x & 63;
  const float* p = s_dstT + (size_t)w * NN;
  float m = -INFINITY;
#pragma unroll
  for (int it = 0; it < 16; ++it) {
    f32x4 v = *(const f32x4*)(p + (it * 64 + lane) * 4);
    m = fmaxf(fmaxf(fmaxf(m, v[0]), v[1]), fmaxf(v[2], v[3]));
  }
#pragma unroll
  for (int s = 1; s < 64; s <<= 1) m = fmaxf(m, __shfl_xor(m, s));
  if (lane == 0) Mh[w] = m;
}

// ---------------------------------------------------------------------------
// Kernel 3: flash-GAT, LDS-staged A with 4-way intra-block reuse.
// Block = (head, 64 i-rows): 256 threads = 4 waves, wave = 16 i-rows, full
// j-range. head = bid&7 -> XCD-pinned: each XCD streams one head's 512KB
// (L2-resident). Per j-tile: stage 8KB A-tile to LDS (source pre-swizzled,
// reads XOR-swizzled -> 2-way banks = free), softmax between stage-issue and
// ds_write hides load latency; 2 blocks/CU overlap the drains.
// Fixed-m softmax -> l wave-local; per-head normalized partials to pout.
// ---------------------------------------------------------------------------
__global__ __launch_bounds__(256, 2) void gat_flash(
    const u64* __restrict__ bits, const u16* __restrict__ Hbt,
    const float* __restrict__ s_srcT, const float* __restrict__ s_dstT,
    const float* __restrict__ Mh, float* __restrict__ pout)
{
  __shared__ u16 Ast[4096];   // one 8KB A-tile [f 0..63][j 0..63], swizzled

  const int t = threadIdx.x, lane = t & 63, wid = t >> 6;
  const int bid = blockIdx.x;
  const int h = bid & 7, iblk = bid >> 3;
  const int i_loc = lane & 15, g = lane >> 4, j0 = g * 8;
  const int irow = iblk * 64 + wid * 16 + i_loc;

  const float s_i = s_srcT[(size_t)h * NN + irow];
  float m_i = s_i + Mh[h];
  m_i = fmaxf(m_i, 0.2f * m_i);                 // lrelu(s_i + M_h) >= all z
  const float L2E = 1.44269504f;
  const float mL = m_i * L2E;

  const u16* tile0 = Hbt + (size_t)h * 64 * 4096;   // + jt*4096
  const float* dT = s_dstT + (size_t)h * NN;
  const u64* brow = bits + (size_t)irow * 64;

  // staging: thread t handles LDS elems [t*8, t*8+8) and [2048+t*8, ...).
  // LDS[row][cb] holds global col (cb ^ ((row&7)<<4)) -> pre-swizzled source.
  const int r0 = t >> 3, colE = (t & 7) * 8;
  const u16* gsrc0 = tile0 + r0 * 64 + (colE ^ ((r0 & 7) << 3));
  const int r1 = 32 + r0;
  const u16* gsrc1 = tile0 + r1 * 64 + (colE ^ ((r1 & 7) << 3));

  const int swz = (i_loc & 7) << 4;
  const char* lbase = (const char*)Ast;

  f32x4 acc[4] = {};
  f32x4 lacc = {0.f, 0.f, 0.f, 0.f};

#define QUAD(DV, MBITS, SH, PW0, PW1, LI) do {                        \
    float z0 = s_i + DV[0], z1 = s_i + DV[1];                         \
    float z2 = s_i + DV[2], z3 = s_i + DV[3];                         \
    z0 = fmaxf(z0, 0.2f * z0); z1 = fmaxf(z1, 0.2f * z1);             \
    z2 = fmaxf(z2, 0.2f * z2); z3 = fmaxf(z3, 0.2f * z3);             \
    float e0 = __builtin_amdgcn_exp2f(__builtin_fmaf(z0, L2E, -mL));  \
    float e1 = __builtin_amdgcn_exp2f(__builtin_fmaf(z1, L2E, -mL));  \
    float e2 = __builtin_amdgcn_exp2f(__builtin_fmaf(z2, L2E, -mL));  \
    float e3 = __builtin_amdgcn_exp2f(__builtin_fmaf(z3, L2E, -mL));  \
    e0 = ((MBITS >> (SH + 0)) & 1u) ? e0 : 0.f;                       \
    e1 = ((MBITS >> (SH + 1)) & 1u) ? e1 : 0.f;                       \
    e2 = ((MBITS >> (SH + 2)) & 1u) ? e2 : 0.f;                       \
    e3 = ((MBITS >> (SH + 3)) & 1u) ? e3 : 0.f;                       \
    lacc[LI] += (e0 + e1) + (e2 + e3);                                \
    PW0 = cvt_pk_bf16(e0, e1); PW1 = cvt_pk_bf16(e2, e3);             \
  } while (0)

  u64 am_n = brow[0];
  f32x4 d_n0 = *(const f32x4*)(dT + j0);
  f32x4 d_n1 = *(const f32x4*)(dT + j0 + 4);
  f32x4 d_n2 = *(const f32x4*)(dT + 32 + j0);
  f32x4 d_n3 = *(const f32x4*)(dT + 36 + j0);

  for (int jt = 0; jt < 64; ++jt) {
    // issue this tile's staging loads (consumed after softmax)
    s16x8 sv0 = *(const s16x8*)(gsrc0 + jt * 4096);
    s16x8 sv1 = *(const s16x8*)(gsrc1 + jt * 4096);

    // softmax for current tile from prefetched mask/d; prefetch next
    const u64 am_ = am_n;
    f32x4 d0 = d_n0, d1 = d_n1, d2 = d_n2, d3 = d_n3;
    const int jn = (jt + 1 < 64) ? jt + 1 : 63;
    am_n = brow[jn];
    d_n0 = *(const f32x4*)(dT + jn * 64 + j0);
    d_n1 = *(const f32x4*)(dT + jn * 64 + j0 + 4);
    d_n2 = *(const f32x4*)(dT + jn * 64 + 32 + j0);
    d_n3 = *(const f32x4*)(dT + jn * 64 + 36 + j0);

    const unsigned amlo = (unsigned)(am_ >> j0);
    const unsigned amhi = (unsigned)(am_ >> (32 + j0));
    union { unsigned w_[4]; s16x8 v_; } P0, P1;
    QUAD(d0, amlo, 0, P0.w_[0], P0.w_[1], 0);
    QUAD(d1, amlo, 4, P0.w_[2], P0.w_[3], 1);
    QUAD(d2, amhi, 0, P1.w_[0], P1.w_[1], 2);
    QUAD(d3, amhi, 4, P1.w_[2], P1.w_[3], 3);

    __syncthreads();              // previous tile's ds_reads all consumed
    *(s16x8*)(Ast + t * 8) = sv0;
    *(s16x8*)(Ast + 2048 + t * 8) = sv1;
    __syncthreads();              // tile staged

#pragma unroll
    for (int fb = 0; fb < 4; ++fb) {
      const int rowb = (fb * 16 + i_loc) * 128;
      s16x8 A0 = *(const s16x8*)(lbase + rowb + ((g * 16) ^ swz));
      s16x8 A1 = *(const s16x8*)(lbase + rowb + (((g * 16) + 64) ^ swz));
      acc[fb] = __builtin_amdgcn_mfma_f32_16x16x32_bf16(A0, P0.v_, acc[fb], 0, 0, 0);
      acc[fb] = __builtin_amdgcn_mfma_f32_16x16x32_bf16(A1, P1.v_, acc[fb], 0, 0, 0);
    }
  }
#undef QUAD

  // l: sum 4 partials, then across the 4 g-groups (full j-range per wave)
  float l_run = (lacc[0] + lacc[1]) + (lacc[2] + lacc[3]);
  l_run += __shfl_xor(l_run, 16);
  l_run += __shfl_xor(l_run, 32);
  const float invL = 1.f / l_run;

  float* ob = pout + ((size_t)h * NN + irow) * 64;
#pragma unroll
  for (int fb = 0; fb < 4; ++fb) {
    f32x4 v = acc[fb] * invL;
    *(f32x4*)(ob + fb * 16 + g * 4) = v;
  }
}

// ---------------------------------------------------------------------------
// Kernel 4: combine 8 per-head partials, apply 1/8 head-mean.
// ---------------------------------------------------------------------------
__global__ __launch_bounds__(256) void gat_combine(
    const float* __restrict__ pout, float* __restrict__ out)
{
  size_t e = (size_t)blockIdx.x * 256 + threadIdx.x;   // f32x4 index
  f32x4 s = {0.f, 0.f, 0.f, 0.f};
#pragma unroll
  for (int h = 0; h < 8; ++h)
    s += ((const f32x4*)pout)[(size_t)h * (NN * 16) + e];
  ((f32x4*)out)[e] = s * 0.125f;
}

extern "C" void kernel_launch(void* const* d_in, const int* in_sizes, int n_in,
                              void* d_out, int out_size, void* d_ws, size_t ws_size,
                              hipStream_t stream)
{
  const float* x = (const float*)d_in[0];
  const void* adj = d_in[1];
  const float* W = (const float*)d_in[2];
  const float* a_src = (const float*)d_in[3];
  const float* a_dst = (const float*)d_in[4];
  float* out = (float*)d_out;

  char* ws = (char*)d_ws;
  float* Hf = (float*)ws;                                   // 8 MB (pout aliases after scores)
  u16* Hbt = (u16*)(ws + 8 * 1024 * 1024);                  // 4 MB [8][64][64][64] bf16 tiled
  float* s_srcT = (float*)(ws + 12 * 1024 * 1024);          // 128 KB [8][4096]
  float* s_dstT = (float*)(ws + 12 * 1024 * 1024 + 128 * 1024);
  int* flag = (int*)(ws + 12 * 1024 * 1024 + 256 * 1024);
  float* Mh = (float*)(ws + 12 * 1024 * 1024 + 384 * 1024); // 32 B
  u64* bits = (u64*)(ws + 12 * 1024 * 1024 + 512 * 1024);   // 2 MB
  float* pout = (float*)ws;                                 // alias Hf (dead after scores) [8][4096][64]

  gat_detect<<<1, 64, 0, stream>>>(adj, flag);
  gat_pack<<<2048, 256, 0, stream>>>(adj, flag, bits);
  gat_gemm1<<<dim3(64, 8), 256, 0, stream>>>(x, W, Hf, Hbt);
  gat_scores<<<1024, 256, 0, stream>>>(Hf, a_src, a_dst, s_srcT, s_dstT);
  gat_dmax<<<1, 512, 0, stream>>>(s_dstT, Mh);
  gat_flash<<<512, 256, 0, stream>>>(bits, Hbt, s_srcT, s_dstT, Mh, pout);
  gat_combine<<<256, 256, 0, stream>>>(pout, out);
}

// Round 10
// 100.274 us; speedup vs baseline: 1.9730x; 1.1009x over previous
//
#include <hip/hip_runtime.h>

#define NN 4096
#define IN_DIM 256
#define HID 64
#define HEADS 8

typedef __attribute__((ext_vector_type(4))) float f32x4;
typedef __attribute__((ext_vector_type(8))) short s16x8;
typedef unsigned short u16;
typedef unsigned long long u64;

__device__ inline u16 f2bf(float f) {
  union { float f; unsigned u; } v; v.f = f;
  unsigned r = (v.u + 0x7FFFu + ((v.u >> 16) & 1u)) >> 16;
  return (u16)r;
}
__device__ inline float bf2f(u16 b) {
  union { unsigned u; float f; } v; v.u = ((unsigned)b) << 16;
  return v.f;
}
__device__ __forceinline__ unsigned cvt_pk_bf16(float a, float b) {
  unsigned r;
  asm("v_cvt_pk_bf16_f32 %0, %1, %2" : "=v"(r) : "v"(a), "v"(b));
  return r;  // lo = bf16(a), hi = bf16(b)
}

// ---------------------------------------------------------------------------
// Kernel 0: detect adjacency element width (uint8 / int32 / int64).
// ---------------------------------------------------------------------------
__global__ void gat_detect(const void* __restrict__ adj, int* __restrict__ flag)
{
  const int lane = threadIdx.x;
  const unsigned char* a8 = (const unsigned char*)adj;
  const int* a32 = (const int*)adj;

  size_t i8 = (size_t)(4 * lane + 1) * 4097;      // diag byte if u8
  int p8 = a8[i8] != 0;

  size_t k = (size_t)(2 * lane + 1);              // odd
  int p32 = a32[k * 4097] != 0;                   // diag elem if i32
  int p64 = a32[2 * k * 4097] != 0;               // low word of diag if i64

  int ok8 = __all(p8), ok32 = __all(p32), ok64 = __all(p64);
  if (lane == 0) *flag = ok8 ? 0 : (ok32 ? 1 : (ok64 ? 2 : 1));
}

// ---------------------------------------------------------------------------
// Kernel 0b: pack adjacency into bitmask [4096 rows][64 u64 words].
// ---------------------------------------------------------------------------
__global__ __launch_bounds__(256) void gat_pack(
    const void* __restrict__ adj, const int* __restrict__ flag,
    u64* __restrict__ bits)
{
  const int mode = *flag;
  const int lane = threadIdx.x & 63;
  const int wave = (blockIdx.x * blockDim.x + threadIdx.x) >> 6;
  const int nwaves = (gridDim.x * blockDim.x) >> 6;
  const size_t nwords = (size_t)NN * NN / 64;

  for (size_t w = wave; w < nwords; w += nwaves) {
    size_t e = w * 64 + lane;
    int on;
    if (mode == 1)      on = ((const int*)adj)[e] != 0;
    else if (mode == 0) on = ((const unsigned char*)adj)[e] != 0;
    else                on = ((const long long*)adj)[e] != 0;
    u64 b = __ballot(on);
    if (lane == 0) bits[w] = b;
  }
}

// ---------------------------------------------------------------------------
// Kernel 1: H = x @ W^T, TILED bf16 out Hbt2[h][jt][f][j_in], PLUS src/dst
// scores computed in the epilogue (the block holds each node's full hidden
// vector in-register) -> no f32 H buffer, no separate scores kernel.
// ---------------------------------------------------------------------------
__global__ __launch_bounds__(256) void gat_gemm1(
    const float* __restrict__ x, const float* __restrict__ W,
    const float* __restrict__ a_src, const float* __restrict__ a_dst,
    u16* __restrict__ Hbt, float* __restrict__ s_srcT,
    float* __restrict__ s_dstT)
{
  __shared__ u16 xhi[64 * 72], xlo[64 * 72], whi[64 * 72], wlo[64 * 72];
  const int nb = blockIdx.x;   // node block (rows) == j-tile index
  const int ob = blockIdx.y;   // out block  (cols) == head
  const int t = threadIdx.x;
  const int lane = t & 63, wid = t >> 6;
  const int wr = wid >> 1, wc = wid & 1;
  const int g = lane >> 4;

  f32x4 acc[2][2] = {};

  const int sn = t >> 2;          // staging row 0..63
  const int skc = (t & 3) * 16;   // staging k offset within 64-chunk

  for (int kb = 0; kb < 4; ++kb) {
    const float* xr = x + (size_t)(nb * 64 + sn) * IN_DIM + kb * 64 + skc;
    const float* wr_p = W + (size_t)(ob * 64 + sn) * IN_DIM + kb * 64 + skc;
#pragma unroll
    for (int c = 0; c < 4; ++c) {
      float4 xv = ((const float4*)xr)[c];
      float4 wv = ((const float4*)wr_p)[c];
      float xf[4] = {xv.x, xv.y, xv.z, xv.w};
      float wf[4] = {wv.x, wv.y, wv.z, wv.w};
      u16 xh[4], xl[4], wh[4], wl[4];
#pragma unroll
      for (int e = 0; e < 4; ++e) {
        xh[e] = f2bf(xf[e]); xl[e] = f2bf(xf[e] - bf2f(xh[e]));
        wh[e] = f2bf(wf[e]); wl[e] = f2bf(wf[e] - bf2f(wh[e]));
      }
      int base = sn * 72 + skc + c * 4;
      *(ushort4*)(xhi + base) = make_ushort4(xh[0], xh[1], xh[2], xh[3]);
      *(ushort4*)(xlo + base) = make_ushort4(xl[0], xl[1], xl[2], xl[3]);
      *(ushort4*)(whi + base) = make_ushort4(wh[0], wh[1], wh[2], wh[3]);
      *(ushort4*)(wlo + base) = make_ushort4(wl[0], wl[1], wl[2], wl[3]);
    }
    __syncthreads();
#pragma unroll
    for (int ks = 0; ks < 2; ++ks) {
      const int k0 = ks * 32 + g * 8;
      s16x8 ah[2], al[2], bh[2], bl[2];
#pragma unroll
      for (int nf = 0; nf < 2; ++nf) {
        int row = wr * 32 + nf * 16 + (lane & 15);
        ah[nf] = *(const s16x8*)(xhi + row * 72 + k0);
        al[nf] = *(const s16x8*)(xlo + row * 72 + k0);
      }
#pragma unroll
      for (int of = 0; of < 2; ++of) {
        int row = wc * 32 + of * 16 + (lane & 15);
        bh[of] = *(const s16x8*)(whi + row * 72 + k0);
        bl[of] = *(const s16x8*)(wlo + row * 72 + k0);
      }
#pragma unroll
      for (int nf = 0; nf < 2; ++nf)
#pragma unroll
        for (int of = 0; of < 2; ++of) {
          acc[nf][of] = __builtin_amdgcn_mfma_f32_16x16x32_bf16(ah[nf], bh[of], acc[nf][of], 0, 0, 0);
          acc[nf][of] = __builtin_amdgcn_mfma_f32_16x16x32_bf16(ah[nf], bl[of], acc[nf][of], 0, 0, 0);
          acc[nf][of] = __builtin_amdgcn_mfma_f32_16x16x32_bf16(al[nf], bh[of], acc[nf][of], 0, 0, 0);
        }
    }
    __syncthreads();
  }

  // ---- epilogue ----
  // (a) transpose C into LDS for the tiled bf16 copy
  u16* Ct = xhi;  // [64 o][72 n]
#pragma unroll
  for (int nf = 0; nf < 2; ++nf)
#pragma unroll
    for (int of = 0; of < 2; ++of)
#pragma unroll
      for (int r = 0; r < 4; ++r) {
        int nloc = wr * 32 + nf * 16 + g * 4 + r;
        int oloc = wc * 32 + of * 16 + (lane & 15);
        Ct[oloc * 72 + nloc] = f2bf(acc[nf][of][r]);
      }

  // (b) src/dst scores: per-thread dot with a_src/a_dst, 16-lane shfl reduce,
  //     cross-wave (wc) add via small LDS.
  {
    const float* asp = a_src + ob * 64;
    const float* adp = a_dst + ob * 64;
    float as0 = asp[wc * 32 + (lane & 15)], as1 = asp[wc * 32 + 16 + (lane & 15)];
    float ad0 = adp[wc * 32 + (lane & 15)], ad1 = adp[wc * 32 + 16 + (lane & 15)];
    float* sred = (float*)wlo;  // [vs: wc*64+node | vd: 128 + wc*64+node]
#pragma unroll
    for (int nf = 0; nf < 2; ++nf)
#pragma unroll
      for (int r = 0; r < 4; ++r) {
        float vs = acc[nf][0][r] * as0 + acc[nf][1][r] * as1;
        float vd = acc[nf][0][r] * ad0 + acc[nf][1][r] * ad1;
#pragma unroll
        for (int m = 1; m < 16; m <<= 1) { vs += __shfl_xor(vs, m); vd += __shfl_xor(vd, m); }
        if ((lane & 15) == 0) {
          int node = wr * 32 + nf * 16 + g * 4 + r;
          sred[wc * 64 + node] = vs;
          sred[128 + wc * 64 + node] = vd;
        }
      }
  }
  __syncthreads();
  {
    int o = t >> 2, nc = (t & 3) * 16;
    u16* dst = Hbt + ((size_t)(ob * 64 + nb) * 64 + o) * 64 + nc;
#pragma unroll
    for (int c = 0; c < 2; ++c) {
      s16x8 v = *(const s16x8*)(Ct + o * 72 + nc + c * 8);
      *(s16x8*)(dst + c * 8) = v;
    }
  }
  if (t < 64) {
    const float* sred = (const float*)wlo;
    s_srcT[(size_t)ob * NN + nb * 64 + t] = sred[t] + sred[64 + t];
    s_dstT[(size_t)ob * NN + nb * 64 + t] = sred[128 + t] + sred[192 + t];
  }
}

// ---------------------------------------------------------------------------
// Kernel 2b: per-head global max of dst scores (upper bound for fixed-m).
// ---------------------------------------------------------------------------
__global__ __launch_bounds__(512) void gat_dmax(
    const float* __restrict__ s_dstT, float* __restrict__ Mh)
{
  const int w = threadIdx.x >> 6, lane = threadIdx.x & 63;
  const float* p = s_dstT + (size_t)w * NN;
  float m = -INFINITY;
#pragma unroll
  for (int it = 0; it < 16; ++it) {
    f32x4 v = *(const f32x4*)(p + (it * 64 + lane) * 4);
    m = fmaxf(fmaxf(fmaxf(m, v[0]), v[1]), fmaxf(v[2], v[3]));
  }
#pragma unroll
  for (int s = 1; s < 64; s <<= 1) m = fmaxf(m, __shfl_xor(m, s));
  if (lane == 0) Mh[w] = m;
}

// ---------------------------------------------------------------------------
// Kernel 3: flash-GAT, LDS-staged A, 8 waves = 4 i-subwaves x 2 j-halves.
// Block = (head, 64 i-rows), grid 512 -> 2 blocks/CU = 16 waves/CU.
// Each j-half group stages its own 8KB A-tile (16KB LDS, union'd with the
// f32 merge buffer). Fixed-m softmax -> j-half partials (acc AND l) merge by
// plain addition in the epilogue. head = bid&7 keeps each head's 512KB
// A-slice XCD-pinned in L2.
// ---------------------------------------------------------------------------
__global__ __launch_bounds__(512, 4) void gat_flash(
    const u64* __restrict__ bits, const u16* __restrict__ Hbt,
    const float* __restrict__ s_srcT, const float* __restrict__ s_dstT,
    const float* __restrict__ Mh, float* __restrict__ pout)
{
  __shared__ char shmem[17408];        // union: u16 Ast[2][4096] | float Mbuf[4][16][66]
  __shared__ float Lbuf[8][16];
  u16* Ast = (u16*)shmem;
  float (*Mbuf)[16][66] = (float(*)[16][66])shmem;

  const int t = threadIdx.x, lane = t & 63, wid = t >> 6;
  const int ws4 = wid & 3, jh = wid >> 2;
  const int bid = blockIdx.x;
  const int h = bid & 7, iblk = bid >> 3;
  const int i_loc = lane & 15, g = lane >> 4, j0 = g * 8;
  const int irow = iblk * 64 + ws4 * 16 + i_loc;

  const float s_i = s_srcT[(size_t)h * NN + irow];
  float m_i = s_i + Mh[h];
  m_i = fmaxf(m_i, 0.2f * m_i);                 // lrelu(s_i + M_h) >= all z
  const float L2E = 1.44269504f;
  const float mL = m_i * L2E;

  const u16* tile0 = Hbt + (size_t)h * 64 * 4096;   // + jt*4096
  const float* dT = s_dstT + (size_t)h * NN;
  const u64* brow = bits + (size_t)irow * 64;

  // staging: group jh (256 threads, lt = t&255) stages its own tile.
  // LDS[row][cb] holds global col (cb ^ ((row&7)<<3 elems)) -> pre-swizzled src.
  const int lt = t & 255;
  const int r0 = lt >> 3, colE = (lt & 7) * 8;
  const u16* gsrc0 = tile0 + r0 * 64 + (colE ^ ((r0 & 7) << 3));
  const int r1 = 32 + r0;
  const u16* gsrc1 = tile0 + r1 * 64 + (colE ^ ((r1 & 7) << 3));
  u16* sdst = Ast + jh * 4096;
  const char* lbase = (const char*)(Ast + jh * 4096);
  const int swz = (i_loc & 7) << 4;

  f32x4 acc[4] = {};
  f32x4 lacc = {0.f, 0.f, 0.f, 0.f};

#define QUAD(DV, MBITS, SH, PW0, PW1, LI) do {                        \
    float z0 = s_i + DV[0], z1 = s_i + DV[1];                         \
    float z2 = s_i + DV[2], z3 = s_i + DV[3];                         \
    z0 = fmaxf(z0, 0.2f * z0); z1 = fmaxf(z1, 0.2f * z1);             \
    z2 = fmaxf(z2, 0.2f * z2); z3 = fmaxf(z3, 0.2f * z3);             \
    float e0 = __builtin_amdgcn_exp2f(__builtin_fmaf(z0, L2E, -mL));  \
    float e1 = __builtin_amdgcn_exp2f(__builtin_fmaf(z1, L2E, -mL));  \
    float e2 = __builtin_amdgcn_exp2f(__builtin_fmaf(z2, L2E, -mL));  \
    float e3 = __builtin_amdgcn_exp2f(__builtin_fmaf(z3, L2E, -mL));  \
    e0 = ((MBITS >> (SH + 0)) & 1u) ? e0 : 0.f;                       \
    e1 = ((MBITS >> (SH + 1)) & 1u) ? e1 : 0.f;                       \
    e2 = ((MBITS >> (SH + 2)) & 1u) ? e2 : 0.f;                       \
    e3 = ((MBITS >> (SH + 3)) & 1u) ? e3 : 0.f;                       \
    lacc[LI] += (e0 + e1) + (e2 + e3);                                \
    PW0 = cvt_pk_bf16(e0, e1); PW1 = cvt_pk_bf16(e2, e3);             \
  } while (0)

  const int jt0 = jh * 32;
  u64 am_n = brow[jt0];
  f32x4 d_n0 = *(const f32x4*)(dT + jt0 * 64 + j0);
  f32x4 d_n1 = *(const f32x4*)(dT + jt0 * 64 + j0 + 4);
  f32x4 d_n2 = *(const f32x4*)(dT + jt0 * 64 + 32 + j0);
  f32x4 d_n3 = *(const f32x4*)(dT + jt0 * 64 + 36 + j0);

  for (int it = 0; it < 32; ++it) {
    const int jt = jt0 + it;
    // issue this tile's staging loads (consumed after softmax)
    s16x8 sv0 = *(const s16x8*)(gsrc0 + jt * 4096);
    s16x8 sv1 = *(const s16x8*)(gsrc1 + jt * 4096);

    // softmax for current tile from prefetched mask/d; prefetch next
    const u64 am_ = am_n;
    f32x4 d0 = d_n0, d1 = d_n1, d2 = d_n2, d3 = d_n3;
    const int jn = jt0 + ((it + 1 < 32) ? it + 1 : 31);
    am_n = brow[jn];
    d_n0 = *(const f32x4*)(dT + jn * 64 + j0);
    d_n1 = *(const f32x4*)(dT + jn * 64 + j0 + 4);
    d_n2 = *(const f32x4*)(dT + jn * 64 + 32 + j0);
    d_n3 = *(const f32x4*)(dT + jn * 64 + 36 + j0);

    const unsigned amlo = (unsigned)(am_ >> j0);
    const unsigned amhi = (unsigned)(am_ >> (32 + j0));
    union { unsigned w_[4]; s16x8 v_; } P0, P1;
    QUAD(d0, amlo, 0, P0.w_[0], P0.w_[1], 0);
    QUAD(d1, amlo, 4, P0.w_[2], P0.w_[3], 1);
    QUAD(d2, amhi, 0, P1.w_[0], P1.w_[1], 2);
    QUAD(d3, amhi, 4, P1.w_[2], P1.w_[3], 3);

    __syncthreads();              // previous tile's ds_reads all consumed
    *(s16x8*)(sdst + lt * 8) = sv0;
    *(s16x8*)(sdst + 2048 + lt * 8) = sv1;
    __syncthreads();              // tile staged

#pragma unroll
    for (int fb = 0; fb < 4; ++fb) {
      const int rowb = (fb * 16 + i_loc) * 128;
      s16x8 A0 = *(const s16x8*)(lbase + rowb + ((g * 16) ^ swz));
      s16x8 A1 = *(const s16x8*)(lbase + rowb + (((g * 16) + 64) ^ swz));
      acc[fb] = __builtin_amdgcn_mfma_f32_16x16x32_bf16(A0, P0.v_, acc[fb], 0, 0, 0);
      acc[fb] = __builtin_amdgcn_mfma_f32_16x16x32_bf16(A1, P1.v_, acc[fb], 0, 0, 0);
    }
  }
#undef QUAD

  // l: sum 4 partials, then across the 4 g-groups (per-row total for this half)
  float l_run = (lacc[0] + lacc[1]) + (lacc[2] + lacc[3]);
  l_run += __shfl_xor(l_run, 16);
  l_run += __shfl_xor(l_run, 32);
  if (lane < 16) Lbuf[wid][i_loc] = l_run;

  __syncthreads();                // loop's LDS reads done; Lbuf visible
  if (jh == 1) {
#pragma unroll
    for (int fb = 0; fb < 4; ++fb)
      *(f32x4*)&Mbuf[ws4][i_loc][fb * 16 + g * 4] = acc[fb];
  }
  __syncthreads();
  if (jh == 0) {
    const float invL = 1.f / (l_run + Lbuf[wid + 4][i_loc]);
    float* ob = pout + ((size_t)h * NN + irow) * 64;
#pragma unroll
    for (int fb = 0; fb < 4; ++fb) {
      f32x4 v = (acc[fb] + *(const f32x4*)&Mbuf[ws4][i_loc][fb * 16 + g * 4]) * invL;
      *(f32x4*)(ob + fb * 16 + g * 4) = v;
    }
  }
}

// ---------------------------------------------------------------------------
// Kernel 4: combine 8 per-head partials, apply 1/8 head-mean.
// ---------------------------------------------------------------------------
__global__ __launch_bounds__(256) void gat_combine(
    const float* __restrict__ pout, float* __restrict__ out)
{
  size_t e = (size_t)blockIdx.x * 256 + threadIdx.x;   // f32x4 index
  f32x4 s = {0.f, 0.f, 0.f, 0.f};
#pragma unroll
  for (int h = 0; h < 8; ++h)
    s += ((const f32x4*)pout)[(size_t)h * (NN * 16) + e];
  ((f32x4*)out)[e] = s * 0.125f;
}

extern "C" void kernel_launch(void* const* d_in, const int* in_sizes, int n_in,
                              void* d_out, int out_size, void* d_ws, size_t ws_size,
                              hipStream_t stream)
{
  const float* x = (const float*)d_in[0];
  const void* adj = d_in[1];
  const float* W = (const float*)d_in[2];
  const float* a_src = (const float*)d_in[3];
  const float* a_dst = (const float*)d_in[4];
  float* out = (float*)d_out;

  char* ws = (char*)d_ws;
  float* pout = (float*)ws;                                 // 8 MB [8][4096][64]
  u16* Hbt = (u16*)(ws + 8 * 1024 * 1024);                  // 4 MB [8][64][64][64] bf16 tiled
  float* s_srcT = (float*)(ws + 12 * 1024 * 1024);          // 128 KB [8][4096]
  float* s_dstT = (float*)(ws + 12 * 1024 * 1024 + 128 * 1024);
  int* flag = (int*)(ws + 12 * 1024 * 1024 + 256 * 1024);
  float* Mh = (float*)(ws + 12 * 1024 * 1024 + 384 * 1024); // 32 B
  u64* bits = (u64*)(ws + 12 * 1024 * 1024 + 512 * 1024);   // 2 MB

  gat_detect<<<1, 64, 0, stream>>>(adj, flag);
  gat_pack<<<2048, 256, 0, stream>>>(adj, flag, bits);
  gat_gemm1<<<dim3(64, 8), 256, 0, stream>>>(x, W, a_src, a_dst, Hbt, s_srcT, s_dstT);
  gat_dmax<<<1, 512, 0, stream>>>(s_dstT, Mh);
  gat_flash<<<512, 512, 0, stream>>>(bits, Hbt, s_srcT, s_dstT, Mh, pout);
  gat_combine<<<256, 256, 0, stream>>>(pout, out);
}